// Round 1
// baseline (151.612 us; speedup 1.0000x reference)
//
#include <hip/hip_runtime.h>
#include <math.h>

#define MM 64
#define NA 24
#define NP 276
#define NT 6000
#define QC 0.22360679774997896f
#define EXPC 0.01666666666666667f  // 5/(3*sig^2), sig=10

// ---------- kernel 1: xs[m,p] = 1/dist(pair p), uu[m] = sum_p xs^2 ----------
__global__ __launch_bounds__(64) void k_prep(const float* __restrict__ Rs,
                                             float* __restrict__ xs,
                                             float* __restrict__ uu) {
  int m = blockIdx.x;
  int lane = threadIdx.x;
  __shared__ float sR[NA * 3];
  for (int idx = lane; idx < NA * 3; idx += 64) sR[idx] = Rs[m * NA * 3 + idx];
  __syncthreads();
  float acc = 0.f;
  for (int p = lane; p < NP; p += 64) {
    int i = (int)((1.0f + sqrtf(1.0f + 8.0f * (float)p)) * 0.5f);
    while (i * (i - 1) / 2 > p) i--;
    while ((i + 1) * i / 2 <= p) i++;
    int j = p - i * (i - 1) / 2;
    float dx = sR[i * 3 + 0] - sR[j * 3 + 0];
    float dy = sR[i * 3 + 1] - sR[j * 3 + 1];
    float dz = sR[i * 3 + 2] - sR[j * 3 + 2];
    float d2 = dx * dx + dy * dy + dz * dz;
    float u = 1.0f / sqrtf(d2);
    xs[m * NP + p] = u;
    acc += u * u;
  }
  for (int off = 32; off; off >>= 1) acc += __shfl_down(acc, off);
  if (lane == 0) uu[m] = acc;
}

// ---------- kernel 2: per-training-row stats vv[t]=|xt|^2, c1[t]=xt.J ----------
__global__ __launch_bounds__(256) void k_stats(const float* __restrict__ xt,
                                               const float* __restrict__ Ja,
                                               float* __restrict__ vv,
                                               float* __restrict__ c1) {
  int t = blockIdx.x * 4 + (threadIdx.x >> 6);
  int lane = threadIdx.x & 63;
  if (t >= NT) return;
  const float* vrow = xt + t * NP;
  const float* jrow = Ja + t * NP;
  float a = 0.f, b = 0.f;
  for (int p = lane; p < NP; p += 64) {
    float v = vrow[p];
    float j = jrow[p];
    a += v * v;
    b += v * j;
  }
  for (int off = 32; off; off >>= 1) {
    a += __shfl_down(a, off);
    b += __shfl_down(b, off);
  }
  if (lane == 0) { vv[t] = a; c1[t] = b; }
}

// ---------- kernel 3: GEMM1 uv[m,t]=xs.xt_t, uJ[m,t]=xs.J_t ----------
// tile 64m x 32t, kb=16, K padded 276->288
__global__ __launch_bounds__(256) void k_gemm1(const float* __restrict__ xs,
                                               const float* __restrict__ xt,
                                               const float* __restrict__ Ja,
                                               float* __restrict__ uv,
                                               float* __restrict__ uJ) {
  __shared__ float As[16][64];     // [k][m]
  __shared__ float2 Bs[16][32];    // [k][t] = (v, j)
  const int tid = threadIdx.x;
  const int t0 = blockIdx.x * 32;
  const int c = tid & 31;          // t column
  const int r = tid >> 5;          // m-group: m = r*8 + i
  const int am = tid >> 2;         // staging: m row 0..63
  const int ak = (tid & 3) << 2;   // staging: k offset 0,4,8,12
  const int bmat = tid >> 7;       // 0 -> xt, 1 -> Ja
  const int brow = (tid >> 2) & 31;
  const int bp = (tid & 3) << 2;
  const float* bsrc = bmat ? Ja : xt;
  float accv[8] = {0.f, 0.f, 0.f, 0.f, 0.f, 0.f, 0.f, 0.f};
  float accj[8] = {0.f, 0.f, 0.f, 0.f, 0.f, 0.f, 0.f, 0.f};
  for (int p0 = 0; p0 < 288; p0 += 16) {
    float4 av = make_float4(0.f, 0.f, 0.f, 0.f);
    int pa = p0 + ak;
    if (pa <= NP - 4) av = *(const float4*)(xs + am * NP + pa);
    float4 bv = make_float4(0.f, 0.f, 0.f, 0.f);
    int pb = p0 + bp;
    int tg = t0 + brow;
    if (pb <= NP - 4 && tg < NT) bv = *(const float4*)(bsrc + tg * NP + pb);
    __syncthreads();
    As[ak + 0][am] = av.x; As[ak + 1][am] = av.y;
    As[ak + 2][am] = av.z; As[ak + 3][am] = av.w;
    if (bmat == 0) {
      Bs[bp + 0][brow].x = bv.x; Bs[bp + 1][brow].x = bv.y;
      Bs[bp + 2][brow].x = bv.z; Bs[bp + 3][brow].x = bv.w;
    } else {
      Bs[bp + 0][brow].y = bv.x; Bs[bp + 1][brow].y = bv.y;
      Bs[bp + 2][brow].y = bv.z; Bs[bp + 3][brow].y = bv.w;
    }
    __syncthreads();
#pragma unroll
    for (int k = 0; k < 16; k++) {
      float2 b = Bs[k][c];
      const float* arow = &As[k][r << 3];
#pragma unroll
      for (int i = 0; i < 8; i++) {
        float a = arow[i];
        accv[i] = fmaf(a, b.x, accv[i]);
        accj[i] = fmaf(a, b.y, accj[i]);
      }
    }
  }
  int t = t0 + c;
  if (t < NT) {
#pragma unroll
    for (int i = 0; i < 8; i++) {
      uv[(r * 8 + i) * NT + t] = accv[i];
      uJ[(r * 8 + i) * NT + t] = accj[i];
    }
  }
}

// ---------- kernel 4: elementwise [M,T] -> w (over uv), e1 (over uJ), Es/sumw ----------
__global__ __launch_bounds__(256) void k_elem(const float* __restrict__ uu,
                                              const float* __restrict__ vv,
                                              const float* __restrict__ c1,
                                              float* __restrict__ uv,
                                              float* __restrict__ uJ,
                                              float* __restrict__ es_acc,
                                              float* __restrict__ sumw) {
  int m = blockIdx.y;
  int t = blockIdx.x * 256 + threadIdx.x;
  float es_p = 0.f, sw_p = 0.f;
  if (t < NT) {
    float g1 = uv[m * NT + t];
    float g2 = uJ[m * NT + t];
    float d2 = uu[m] - 2.f * g1 + vv[t];
    d2 = fmaxf(d2, 0.f);
    float xd = QC * sqrtf(d2);
    float dv = QC * (g2 - c1[t]);
    float ex = EXPC * __expf(-xd);
    float e1v = ex * (1.f + xd);
    float wv = ex * dv;
    uv[m * NT + t] = wv;
    uJ[m * NT + t] = e1v;
    es_p = e1v * dv;
    sw_p = wv;
  }
  for (int off = 32; off; off >>= 1) {
    es_p += __shfl_down(es_p, off);
    sw_p += __shfl_down(sw_p, off);
  }
  __shared__ float s_es[4], s_sw[4];
  int wid = threadIdx.x >> 6;
  if ((threadIdx.x & 63) == 0) { s_es[wid] = es_p; s_sw[wid] = sw_p; }
  __syncthreads();
  if (threadIdx.x == 0) {
    atomicAdd(&es_acc[m], s_es[0] + s_es[1] + s_es[2] + s_es[3]);
    atomicAdd(&sumw[m], s_sw[0] + s_sw[1] + s_sw[2] + s_sw[3]);
  }
}

// ---------- kernel 5: GEMM2 F1p[m,p]=sum_t w*xt, F2[m,p]=sum_t e1*J ----------
// tile 64m x 32p, K split into 24 chunks of 256, fp32 atomic accumulate
__global__ __launch_bounds__(256) void k_gemm2(const float* __restrict__ w,
                                               const float* __restrict__ e1,
                                               const float* __restrict__ xt,
                                               const float* __restrict__ Ja,
                                               float* __restrict__ F1p,
                                               float* __restrict__ F2) {
  __shared__ float2 As[16][64];   // [k][m] = (w, e1)
  __shared__ float2 Bs[16][32];   // [k][p] = (v, j)
  const int tid = threadIdx.x;
  const int p0 = blockIdx.x * 32;
  const int k0 = blockIdx.y * 256;
  const int kend = min(k0 + 256, NT);
  const int c = tid & 31;          // p column
  const int r = tid >> 5;
  const int am = tid >> 2;
  const int ak = (tid & 3) << 2;
  const int bmat = tid >> 7;
  const int bk = (tid >> 3) & 15;
  const int bp = (tid & 7) << 2;
  const float* bsrc = bmat ? Ja : xt;
  float acc1[8] = {0.f, 0.f, 0.f, 0.f, 0.f, 0.f, 0.f, 0.f};
  float acc2[8] = {0.f, 0.f, 0.f, 0.f, 0.f, 0.f, 0.f, 0.f};
  for (int kk = k0; kk < kend; kk += 16) {
    float4 aw = make_float4(0.f, 0.f, 0.f, 0.f);
    float4 ae = make_float4(0.f, 0.f, 0.f, 0.f);
    int tg = kk + ak;
    if (tg + 3 < kend) {
      aw = *(const float4*)(w + am * NT + tg);
      ae = *(const float4*)(e1 + am * NT + tg);
    }
    float4 bv = make_float4(0.f, 0.f, 0.f, 0.f);
    int kg = kk + bk;
    int pg = p0 + bp;
    if (kg < kend && pg <= NP - 4) bv = *(const float4*)(bsrc + kg * NP + pg);
    __syncthreads();
    As[ak + 0][am].x = aw.x; As[ak + 0][am].y = ae.x;
    As[ak + 1][am].x = aw.y; As[ak + 1][am].y = ae.y;
    As[ak + 2][am].x = aw.z; As[ak + 2][am].y = ae.z;
    As[ak + 3][am].x = aw.w; As[ak + 3][am].y = ae.w;
    if (bmat == 0) {
      Bs[bk][bp + 0].x = bv.x; Bs[bk][bp + 1].x = bv.y;
      Bs[bk][bp + 2].x = bv.z; Bs[bk][bp + 3].x = bv.w;
    } else {
      Bs[bk][bp + 0].y = bv.x; Bs[bk][bp + 1].y = bv.y;
      Bs[bk][bp + 2].y = bv.z; Bs[bk][bp + 3].y = bv.w;
    }
    __syncthreads();
#pragma unroll
    for (int k = 0; k < 16; k++) {
      float2 b = Bs[k][c];
      const float2* arow = &As[k][r << 3];
#pragma unroll
      for (int i = 0; i < 8; i++) {
        float2 a = arow[i];
        acc1[i] = fmaf(a.x, b.x, acc1[i]);
        acc2[i] = fmaf(a.y, b.y, acc2[i]);
      }
    }
  }
  int p = p0 + c;
  if (p < NP) {
#pragma unroll
    for (int i = 0; i < 8; i++) {
      atomicAdd(&F1p[(r * 8 + i) * NP + p], acc1[i]);
      atomicAdd(&F2[(r * 8 + i) * NP + p], acc2[i]);
    }
  }
}

// ---------- kernel 6: finalize Fs_x, force gather, Es ----------
__global__ __launch_bounds__(320) void k_final(const float* __restrict__ Rs,
                                               const float* __restrict__ xs,
                                               const float* __restrict__ F1p,
                                               const float* __restrict__ F2,
                                               const float* __restrict__ es_acc,
                                               const float* __restrict__ sumw,
                                               float* __restrict__ out) {
  int m = blockIdx.x;
  int tid = threadIdx.x;
  __shared__ float fx[NP];
  __shared__ float sR[NA * 3];
  if (tid < NA * 3) sR[tid] = Rs[m * NA * 3 + tid];
  float sw = sumw[m];
  for (int p = tid; p < NP; p += 320) {
    float u = xs[m * NP + p];
    float F1 = QC * (u * sw - F1p[m * NP + p]);
    fx[p] = (F1 - F2[m * NP + p]) * u * u * u;
  }
  __syncthreads();
  if (tid == 0) out[m] = es_acc[m] / QC;  // *STD + C with STD=1, C=0
  if (tid < NA * 3) {
    int a = tid / 3, cc = tid % 3;
    float ra = sR[a * 3 + cc];
    float acc = 0.f;
    for (int b = 0; b < NA; b++) {
      if (b == a) continue;
      int i = a > b ? a : b;
      int j = a > b ? b : a;
      int p = i * (i - 1) / 2 + j;
      acc += (sR[b * 3 + cc] - ra) * fx[p];  // Fs[a] = sum_b (R[b]-R[a])*mult
    }
    out[MM + m * NA * 3 + tid] = acc;
  }
}

extern "C" void kernel_launch(void* const* d_in, const int* in_sizes, int n_in,
                              void* d_out, int out_size, void* d_ws, size_t ws_size,
                              hipStream_t stream) {
  const float* Rs = (const float*)d_in[0];
  const float* xt = (const float*)d_in[1];
  const float* Ja = (const float*)d_in[2];
  float* out = (float*)d_out;
  float* ws = (float*)d_ws;
  // workspace layout (floats): total ~833k floats = 3.33 MB
  float* xs  = ws;                  // 64*276
  float* uu  = xs + MM * NP;        // 64
  float* vv  = uu + MM;             // 6000
  float* c1  = vv + NT;             // 6000
  float* F1p = c1 + NT;             // 64*276  (zeroed)
  float* F2  = F1p + MM * NP;       // 64*276  (zeroed)
  float* es  = F2 + MM * NP;        // 64      (zeroed)
  float* sw  = es + MM;             // 64      (zeroed)
  float* uv  = sw + MM;             // 64*6000 (uv -> w in place)
  float* uJ  = uv + MM * NT;        // 64*6000 (uJ -> e1 in place)

  hipMemsetAsync(F1p, 0, (size_t)(2 * MM * NP + 2 * MM) * sizeof(float), stream);
  k_prep<<<MM, 64, 0, stream>>>(Rs, xs, uu);
  k_stats<<<NT / 4, 256, 0, stream>>>(xt, Ja, vv, c1);
  k_gemm1<<<(NT + 31) / 32, 256, 0, stream>>>(xs, xt, Ja, uv, uJ);
  k_elem<<<dim3((NT + 255) / 256, MM), 256, 0, stream>>>(uu, vv, c1, uv, uJ, es, sw);
  k_gemm2<<<dim3((NP + 31) / 32, (NT + 255) / 256), 256, 0, stream>>>(uv, uJ, xt, Ja, F1p, F2);
  k_final<<<MM, 320, 0, stream>>>(Rs, xs, F1p, F2, es, sw, out);
}